// Round 1
// baseline (613.286 us; speedup 1.0000x reference)
//
#include <hip/hip_runtime.h>
#include <math.h>

// Problem constants: x is (16,128,64,512) fp32, viewed as (bp=64, c=32, h=64, w=512)
#define HH 64
#define WW 512

// workspace layout (float offsets)
#define OFF_HSUM 0
#define OFF_HMAX 131072
#define OFF_WSUM 262144
#define OFF_WMAX 1310720
#define OFF_PH   2359296
#define OFF_PW   2490368
// total = 3538944 floats = ~13.5 MiB

__device__ __forceinline__ float wred_sum(float v) {
#pragma unroll
    for (int m = 1; m < 64; m <<= 1) v += __shfl_xor(v, m, 64);
    return v;
}
__device__ __forceinline__ float wred_max(float v) {
#pragma unroll
    for (int m = 1; m < 64; m <<= 1) v = fmaxf(v, __shfl_xor(v, m, 64));
    return v;
}

// ---------------------------------------------------------------------------
// Kernel 1: per (bp,c) slice (64x512), compute row sum/max over W and
// col sum/max over H in ONE pass over x. 2048 blocks x 256 threads (4 waves).
// Wave w handles rows {w, w+4, ...}; each lane reads 2 float4 per row.
// ---------------------------------------------------------------------------
__global__ __launch_bounds__(256) void k_reduce(const float* __restrict__ x,
                                                float* __restrict__ ws) {
    const int slice = blockIdx.x;           // bp*32 + c
    const int tid  = threadIdx.x;
    const int wave = tid >> 6, lane = tid & 63;
    const float4* x4 = (const float4*)(x + (size_t)slice * (HH * WW));

    float4 cs1 = make_float4(0.f, 0.f, 0.f, 0.f);
    float4 cs2 = make_float4(0.f, 0.f, 0.f, 0.f);
    float4 cm1 = make_float4(-INFINITY, -INFINITY, -INFINITY, -INFINITY);
    float4 cm2 = cm1;

    float* hs = ws + OFF_HSUM + slice * HH;
    float* hm = ws + OFF_HMAX + slice * HH;

#pragma unroll 4
    for (int r = 0; r < 16; ++r) {
        const int h = wave + r * 4;
        const float4 v1 = x4[h * 128 + lane];
        const float4 v2 = x4[h * 128 + 64 + lane];
        cs1.x += v1.x; cs1.y += v1.y; cs1.z += v1.z; cs1.w += v1.w;
        cs2.x += v2.x; cs2.y += v2.y; cs2.z += v2.z; cs2.w += v2.w;
        cm1.x = fmaxf(cm1.x, v1.x); cm1.y = fmaxf(cm1.y, v1.y);
        cm1.z = fmaxf(cm1.z, v1.z); cm1.w = fmaxf(cm1.w, v1.w);
        cm2.x = fmaxf(cm2.x, v2.x); cm2.y = fmaxf(cm2.y, v2.y);
        cm2.z = fmaxf(cm2.z, v2.z); cm2.w = fmaxf(cm2.w, v2.w);

        float rs = ((v1.x + v1.y) + (v1.z + v1.w)) + ((v2.x + v2.y) + (v2.z + v2.w));
        float rm = fmaxf(fmaxf(fmaxf(v1.x, v1.y), fmaxf(v1.z, v1.w)),
                         fmaxf(fmaxf(v2.x, v2.y), fmaxf(v2.z, v2.w)));
        rs = wred_sum(rs);
        rm = wred_max(rm);
        if (lane == 0) { hs[h] = rs; hm[h] = rm; }
    }

    __shared__ float4 scs[4][128];
    __shared__ float4 scm[4][128];
    scs[wave][lane] = cs1; scs[wave][lane + 64] = cs2;
    scm[wave][lane] = cm1; scm[wave][lane + 64] = cm2;
    __syncthreads();
    if (tid < 128) {
        const float4 a = scs[0][tid], b = scs[1][tid], c = scs[2][tid], d = scs[3][tid];
        float4 s = make_float4(a.x + b.x + c.x + d.x, a.y + b.y + c.y + d.y,
                               a.z + b.z + c.z + d.z, a.w + b.w + c.w + d.w);
        const float4 e = scm[0][tid], f = scm[1][tid], g = scm[2][tid], hq = scm[3][tid];
        float4 m = make_float4(fmaxf(fmaxf(e.x, f.x), fmaxf(g.x, hq.x)),
                               fmaxf(fmaxf(e.y, f.y), fmaxf(g.y, hq.y)),
                               fmaxf(fmaxf(e.z, f.z), fmaxf(g.z, hq.z)),
                               fmaxf(fmaxf(e.w, f.w), fmaxf(g.w, hq.w)));
        ((float4*)(ws + OFF_WSUM + (size_t)slice * WW))[tid] = s;
        ((float4*)(ws + OFF_WMAX + (size_t)slice * WW))[tid] = m;
    }
}

// ---------------------------------------------------------------------------
// Kernel 2: fused convs + relu + softmax.
//  blocks 0..63   : ph path, one block per bp. Computes 32o x 64h conv outputs
//                   (K = 32i*3kh*2kw), relu, softmax over h.
//  blocks 64..575 : pw path, (bp, og) with og = 8 groups of 4 o. Each wave
//                   owns one o and the full 512 w -> shuffle softmax in-wave.
// ---------------------------------------------------------------------------
__global__ __launch_bounds__(256) void k_conv(const float* __restrict__ wh,
                                              const float* __restrict__ bh,
                                              const float* __restrict__ wwt,
                                              const float* __restrict__ bwt,
                                              float* __restrict__ ws) {
    __shared__ float sm[12928];
    const int bid = blockIdx.x;
    const int tid = threadIdx.x;

    if (bid < 64) {
        // ---------------- ph path ----------------
        const int bp = bid;
        float* shA  = sm;                    // [32][66][2]  (h padded +1 both sides)
        float* shWh = sm + 4224;             // [32][32][3][2] flat, same as w_h
        float* tile = sm + 10368;            // [32][64] conv output (post-relu)
        float* red1 = sm + 12416;            // [256]
        float* red2 = sm + 12672;            // [256]

        for (int idx = tid; idx < 32 * 64; idx += 256) {
            const int i = idx >> 6, h = idx & 63;
            const int g = (bp * 32 + i) * 64 + h;
            shA[(i * 66 + h + 1) * 2 + 0] = ws[OFF_HSUM + g] * (1.0f / 512.0f);
            shA[(i * 66 + h + 1) * 2 + 1] = ws[OFF_HMAX + g];
        }
        if (tid < 64) {
            const int i = tid >> 1, e = tid & 1;
            const int hh = e ? 65 : 0;
            shA[(i * 66 + hh) * 2 + 0] = 0.f;
            shA[(i * 66 + hh) * 2 + 1] = 0.f;
        }
        for (int idx = tid; idx < 6144; idx += 256) shWh[idx] = wh[idx];
        __syncthreads();

        // conv: thread = (otile 0..15)*2 o x (htile 0..15)*4 h
        const int otile = tid >> 4, htile = tid & 15;
        const int o0 = otile * 2, h0 = htile * 4;
        float acc[2][4];
#pragma unroll
        for (int oo = 0; oo < 2; ++oo) {
            const float b = bh[o0 + oo];
#pragma unroll
            for (int hh = 0; hh < 4; ++hh) acc[oo][hh] = b;
        }
        for (int i = 0; i < 32; ++i) {
            float xv[6][2];
#pragma unroll
            for (int j = 0; j < 6; ++j) {
                const float2 v = *(const float2*)&shA[(i * 66 + h0 + j) * 2];
                xv[j][0] = v.x; xv[j][1] = v.y;
            }
#pragma unroll
            for (int oo = 0; oo < 2; ++oo) {
                const float* wr = &shWh[((o0 + oo) * 32 + i) * 6];
#pragma unroll
                for (int kh = 0; kh < 3; ++kh) {
#pragma unroll
                    for (int kw = 0; kw < 2; ++kw) {
                        const float wg = wr[kh * 2 + kw];
#pragma unroll
                        for (int hh = 0; hh < 4; ++hh)
                            acc[oo][hh] += wg * xv[hh + kh][kw];
                    }
                }
            }
        }
#pragma unroll
        for (int oo = 0; oo < 2; ++oo)
#pragma unroll
            for (int hh = 0; hh < 4; ++hh)
                tile[(o0 + oo) * 64 + h0 + hh] = fmaxf(acc[oo][hh], 0.f);
        __syncthreads();

        // softmax over h per o: 8 threads per row, 8 h each
        const int o = tid >> 3, k = tid & 7;
        const float* row = &tile[o * 64 + k * 8];
        float m = row[0];
#pragma unroll
        for (int j = 1; j < 8; ++j) m = fmaxf(m, row[j]);
        red1[tid] = m;
        __syncthreads();
        float M = red1[o * 8];
#pragma unroll
        for (int j = 1; j < 8; ++j) M = fmaxf(M, red1[o * 8 + j]);
        float e[8], s = 0.f;
#pragma unroll
        for (int j = 0; j < 8; ++j) { e[j] = __expf(row[j] - M); s += e[j]; }
        red2[tid] = s;
        __syncthreads();
        float S = 0.f;
#pragma unroll
        for (int j = 0; j < 8; ++j) S += red2[o * 8 + j];
        const float inv = 1.0f / S;
        float* dst = ws + OFF_PH + (size_t)(bp * 32 + o) * 64 + k * 8;
#pragma unroll
        for (int j = 0; j < 8; ++j) dst[j] = e[j] * inv;
    } else {
        // ---------------- pw path ----------------
        const int bid2 = bid - 64;
        const int bp = bid2 >> 3, og = bid2 & 7;
        float* shX = sm;                     // [8 ii][2 kh][514]  (w shifted +1)
        float* shW = sm + 8224;              // [4 oo][32 i][2 kh][3 kw]
        const int wave = tid >> 6, lane = tid & 63;
        const int o = og * 4 + wave;

        for (int idx = tid; idx < 768; idx += 256) shW[idx] = wwt[og * 768 + idx];

        float acc[8];
        {
            const float b = bwt[o];
#pragma unroll
            for (int q = 0; q < 8; ++q) acc[q] = b;
        }

        for (int ic = 0; ic < 4; ++ic) {
            __syncthreads();  // also covers shW staging on first iter
            for (int idx = tid; idx < 8192; idx += 256) {
                const int ii = idx >> 10;
                const int rem = idx & 1023;
                const int kh = rem >> 9;
                const int w = rem & 511;
                const int g = (bp * 32 + ic * 8 + ii) * 512 + w;
                const float v = (kh == 0) ? ws[OFF_WSUM + g] * (1.0f / 64.0f)
                                          : ws[OFF_WMAX + g];
                shX[(ii * 2 + kh) * 514 + w + 1] = v;
            }
            if (tid < 16) {
                const int ii = tid >> 1, kh = tid & 1;
                shX[(ii * 2 + kh) * 514 + 0] = 0.f;
                shX[(ii * 2 + kh) * 514 + 513] = 0.f;
            }
            __syncthreads();
#pragma unroll
            for (int ii = 0; ii < 8; ++ii) {
                const int i = ic * 8 + ii;
#pragma unroll
                for (int kh = 0; kh < 2; ++kh) {
                    const float* row = &shX[(ii * 2 + kh) * 514];
                    const float* wr = &shW[wave * 192 + i * 6 + kh * 3];
                    const float w0v = wr[0], w1v = wr[1], w2v = wr[2];
#pragma unroll
                    for (int q = 0; q < 8; ++q) {
                        // this thread's w = q*64 + lane; shifted LDS idx = w + kw
                        const int b = q * 64 + lane;
                        const float v0 = row[b];
                        const float v1 = row[b + 1];
                        const float v2 = row[b + 2];
                        acc[q] += w0v * v0 + w1v * v1 + w2v * v2;
                    }
                }
            }
        }
        // relu + in-wave softmax over the 512 w this wave owns
#pragma unroll
        for (int q = 0; q < 8; ++q) acc[q] = fmaxf(acc[q], 0.f);
        float m = acc[0];
#pragma unroll
        for (int q = 1; q < 8; ++q) m = fmaxf(m, acc[q]);
        m = wred_max(m);
        float e[8], s = 0.f;
#pragma unroll
        for (int q = 0; q < 8; ++q) { e[q] = __expf(acc[q] - m); s += e[q]; }
        s = wred_sum(s);
        const float inv = 1.0f / s;
        float* dst = ws + OFF_PW + (size_t)(bp * 32 + o) * 512;
#pragma unroll
        for (int q = 0; q < 8; ++q) dst[q * 64 + lane] = e[q] * inv;
    }
}

// ---------------------------------------------------------------------------
// Kernel 3: apply. One block per (bp, h): precompute coef[o][c]=w_e[o,c]*ph[c,h]
// in LDS, then each thread does 8o x 8w: amap = b_e + sum_c coef*pw, then
// out = x*(1+sigmoid(amap)). 4096 blocks x 256 threads.
// ---------------------------------------------------------------------------
__global__ __launch_bounds__(256) void k_apply(const float* __restrict__ x,
                                               const float* __restrict__ we,
                                               const float* __restrict__ be,
                                               const float* __restrict__ ws,
                                               float* __restrict__ out) {
    const int bid = blockIdx.x;
    const int bp = bid >> 6;
    const int h = bid & 63;
    const int tid = threadIdx.x;
    const int wave = tid >> 6, lane = tid & 63;

    __shared__ float shPh[32];
    __shared__ float coef[1024];  // [o][c]

    if (tid < 32) shPh[tid] = ws[OFF_PH + (size_t)(bp * 32 + tid) * 64 + h];
    __syncthreads();
    for (int idx = tid; idx < 1024; idx += 256)
        coef[idx] = we[idx] * shPh[idx & 31];
    __syncthreads();

    const int o0 = wave * 8;
    const int w0 = lane * 8;
    float acc[8][8];
#pragma unroll
    for (int oo = 0; oo < 8; ++oo) {
        const float b = be[o0 + oo];
#pragma unroll
        for (int q = 0; q < 8; ++q) acc[oo][q] = b;
    }

    const float4* pw4 = (const float4*)(ws + OFF_PW + (size_t)bp * 32 * 512);
    for (int c = 0; c < 32; ++c) {
        const float4 p0 = pw4[c * 128 + lane * 2];
        const float4 p1 = pw4[c * 128 + lane * 2 + 1];
        const float pv[8] = {p0.x, p0.y, p0.z, p0.w, p1.x, p1.y, p1.z, p1.w};
#pragma unroll
        for (int oo = 0; oo < 8; ++oo) {
            const float wg = coef[(o0 + oo) * 32 + c];  // wave-uniform broadcast
#pragma unroll
            for (int q = 0; q < 8; ++q) acc[oo][q] += wg * pv[q];
        }
    }

#pragma unroll
    for (int oo = 0; oo < 8; ++oo) {
        const size_t base = (((size_t)(bp * 32 + o0 + oo)) * 64 + h) * 512 + w0;
        const float4 xa = *(const float4*)(x + base);
        const float4 xb = *(const float4*)(x + base + 4);
        const float xv[8] = {xa.x, xa.y, xa.z, xa.w, xb.x, xb.y, xb.z, xb.w};
        float r[8];
#pragma unroll
        for (int q = 0; q < 8; ++q) {
            const float a = acc[oo][q];
            const float ex = __expf(-a);
            const float sg = __builtin_amdgcn_rcpf(1.0f + ex);
            r[q] = xv[q] + xv[q] * sg;
        }
        *(float4*)(out + base)     = make_float4(r[0], r[1], r[2], r[3]);
        *(float4*)(out + base + 4) = make_float4(r[4], r[5], r[6], r[7]);
    }
}

extern "C" void kernel_launch(void* const* d_in, const int* in_sizes, int n_in,
                              void* d_out, int out_size, void* d_ws, size_t ws_size,
                              hipStream_t stream) {
    const float* x   = (const float*)d_in[0];
    const float* wh  = (const float*)d_in[1];
    const float* bh  = (const float*)d_in[2];
    const float* wwt = (const float*)d_in[3];
    const float* bwt = (const float*)d_in[4];
    const float* we  = (const float*)d_in[5];
    const float* be  = (const float*)d_in[6];
    float* out = (float*)d_out;
    float* ws  = (float*)d_ws;

    k_reduce<<<2048, 256, 0, stream>>>(x, ws);
    k_conv<<<576, 256, 0, stream>>>(wh, bh, wwt, bwt, ws);
    k_apply<<<4096, 256, 0, stream>>>(x, we, be, ws, out);
}

// Round 2
// 582.779 us; speedup vs baseline: 1.0523x; 1.0523x over previous
//
#include <hip/hip_runtime.h>
#include <math.h>

// Problem constants: x is (16,128,64,512) fp32, viewed as (bp=64, c=32, h=64, w=512)
#define HH 64
#define WW 512

typedef float f4 __attribute__((ext_vector_type(4)));

// workspace layout (float offsets)
#define OFF_HSUM 0
#define OFF_HMAX 131072
#define OFF_WSUM 262144
#define OFF_WMAX 1310720
#define OFF_PH   2359296
#define OFF_PW   2490368
// total = 3538944 floats = ~13.5 MiB

__device__ __forceinline__ float wred_sum(float v) {
#pragma unroll
    for (int m = 1; m < 64; m <<= 1) v += __shfl_xor(v, m, 64);
    return v;
}
__device__ __forceinline__ float wred_max(float v) {
#pragma unroll
    for (int m = 1; m < 64; m <<= 1) v = fmaxf(v, __shfl_xor(v, m, 64));
    return v;
}

// ---------------------------------------------------------------------------
// Kernel 1: per (bp,c) slice (64x512), compute row sum/max over W and
// col sum/max over H in ONE pass over x. 2048 blocks x 256 threads (4 waves).
// ---------------------------------------------------------------------------
__global__ __launch_bounds__(256) void k_reduce(const float* __restrict__ x,
                                                float* __restrict__ ws) {
    const int slice = blockIdx.x;           // bp*32 + c
    const int tid  = threadIdx.x;
    const int wave = tid >> 6, lane = tid & 63;
    const float4* x4 = (const float4*)(x + (size_t)slice * (HH * WW));

    float4 cs1 = make_float4(0.f, 0.f, 0.f, 0.f);
    float4 cs2 = make_float4(0.f, 0.f, 0.f, 0.f);
    float4 cm1 = make_float4(-INFINITY, -INFINITY, -INFINITY, -INFINITY);
    float4 cm2 = cm1;

    float* hs = ws + OFF_HSUM + slice * HH;
    float* hm = ws + OFF_HMAX + slice * HH;

#pragma unroll 4
    for (int r = 0; r < 16; ++r) {
        const int h = wave + r * 4;
        const float4 v1 = x4[h * 128 + lane];
        const float4 v2 = x4[h * 128 + 64 + lane];
        cs1.x += v1.x; cs1.y += v1.y; cs1.z += v1.z; cs1.w += v1.w;
        cs2.x += v2.x; cs2.y += v2.y; cs2.z += v2.z; cs2.w += v2.w;
        cm1.x = fmaxf(cm1.x, v1.x); cm1.y = fmaxf(cm1.y, v1.y);
        cm1.z = fmaxf(cm1.z, v1.z); cm1.w = fmaxf(cm1.w, v1.w);
        cm2.x = fmaxf(cm2.x, v2.x); cm2.y = fmaxf(cm2.y, v2.y);
        cm2.z = fmaxf(cm2.z, v2.z); cm2.w = fmaxf(cm2.w, v2.w);

        float rs = ((v1.x + v1.y) + (v1.z + v1.w)) + ((v2.x + v2.y) + (v2.z + v2.w));
        float rm = fmaxf(fmaxf(fmaxf(v1.x, v1.y), fmaxf(v1.z, v1.w)),
                         fmaxf(fmaxf(v2.x, v2.y), fmaxf(v2.z, v2.w)));
        rs = wred_sum(rs);
        rm = wred_max(rm);
        if (lane == 0) { hs[h] = rs; hm[h] = rm; }
    }

    __shared__ float4 scs[4][128];
    __shared__ float4 scm[4][128];
    scs[wave][lane] = cs1; scs[wave][lane + 64] = cs2;
    scm[wave][lane] = cm1; scm[wave][lane + 64] = cm2;
    __syncthreads();
    if (tid < 128) {
        const float4 a = scs[0][tid], b = scs[1][tid], c = scs[2][tid], d = scs[3][tid];
        float4 s = make_float4(a.x + b.x + c.x + d.x, a.y + b.y + c.y + d.y,
                               a.z + b.z + c.z + d.z, a.w + b.w + c.w + d.w);
        const float4 e = scm[0][tid], f = scm[1][tid], g = scm[2][tid], hq = scm[3][tid];
        float4 m = make_float4(fmaxf(fmaxf(e.x, f.x), fmaxf(g.x, hq.x)),
                               fmaxf(fmaxf(e.y, f.y), fmaxf(g.y, hq.y)),
                               fmaxf(fmaxf(e.z, f.z), fmaxf(g.z, hq.z)),
                               fmaxf(fmaxf(e.w, f.w), fmaxf(g.w, hq.w)));
        ((float4*)(ws + OFF_WSUM + (size_t)slice * WW))[tid] = s;
        ((float4*)(ws + OFF_WMAX + (size_t)slice * WW))[tid] = m;
    }
}

// ---------------------------------------------------------------------------
// Kernel 2: fused convs + relu + softmax.
//  blocks 0..63   : ph path (per bp). blocks 64..575 : pw path (bp, og).
// ---------------------------------------------------------------------------
__global__ __launch_bounds__(256) void k_conv(const float* __restrict__ wh,
                                              const float* __restrict__ bh,
                                              const float* __restrict__ wwt,
                                              const float* __restrict__ bwt,
                                              float* __restrict__ ws) {
    __shared__ float sm[12928];
    const int bid = blockIdx.x;
    const int tid = threadIdx.x;

    if (bid < 64) {
        // ---------------- ph path ----------------
        const int bp = bid;
        float* shA  = sm;                    // [32][66][2]
        float* shWh = sm + 4224;             // [32][32][3][2]
        float* tile = sm + 10368;            // [32][64]
        float* red1 = sm + 12416;            // [256]
        float* red2 = sm + 12672;            // [256]

        for (int idx = tid; idx < 32 * 64; idx += 256) {
            const int i = idx >> 6, h = idx & 63;
            const int g = (bp * 32 + i) * 64 + h;
            shA[(i * 66 + h + 1) * 2 + 0] = ws[OFF_HSUM + g] * (1.0f / 512.0f);
            shA[(i * 66 + h + 1) * 2 + 1] = ws[OFF_HMAX + g];
        }
        if (tid < 64) {
            const int i = tid >> 1, e = tid & 1;
            const int hh = e ? 65 : 0;
            shA[(i * 66 + hh) * 2 + 0] = 0.f;
            shA[(i * 66 + hh) * 2 + 1] = 0.f;
        }
        for (int idx = tid; idx < 6144; idx += 256) shWh[idx] = wh[idx];
        __syncthreads();

        const int otile = tid >> 4, htile = tid & 15;
        const int o0 = otile * 2, h0 = htile * 4;
        float acc[2][4];
#pragma unroll
        for (int oo = 0; oo < 2; ++oo) {
            const float b = bh[o0 + oo];
#pragma unroll
            for (int hh = 0; hh < 4; ++hh) acc[oo][hh] = b;
        }
        for (int i = 0; i < 32; ++i) {
            float xv[6][2];
#pragma unroll
            for (int j = 0; j < 6; ++j) {
                const float2 v = *(const float2*)&shA[(i * 66 + h0 + j) * 2];
                xv[j][0] = v.x; xv[j][1] = v.y;
            }
#pragma unroll
            for (int oo = 0; oo < 2; ++oo) {
                const float* wr = &shWh[((o0 + oo) * 32 + i) * 6];
#pragma unroll
                for (int kh = 0; kh < 3; ++kh) {
#pragma unroll
                    for (int kw = 0; kw < 2; ++kw) {
                        const float wg = wr[kh * 2 + kw];
#pragma unroll
                        for (int hh = 0; hh < 4; ++hh)
                            acc[oo][hh] += wg * xv[hh + kh][kw];
                    }
                }
            }
        }
#pragma unroll
        for (int oo = 0; oo < 2; ++oo)
#pragma unroll
            for (int hh = 0; hh < 4; ++hh)
                tile[(o0 + oo) * 64 + h0 + hh] = fmaxf(acc[oo][hh], 0.f);
        __syncthreads();

        const int o = tid >> 3, k = tid & 7;
        const float* row = &tile[o * 64 + k * 8];
        float m = row[0];
#pragma unroll
        for (int j = 1; j < 8; ++j) m = fmaxf(m, row[j]);
        red1[tid] = m;
        __syncthreads();
        float M = red1[o * 8];
#pragma unroll
        for (int j = 1; j < 8; ++j) M = fmaxf(M, red1[o * 8 + j]);
        float e[8], s = 0.f;
#pragma unroll
        for (int j = 0; j < 8; ++j) { e[j] = __expf(row[j] - M); s += e[j]; }
        red2[tid] = s;
        __syncthreads();
        float S = 0.f;
#pragma unroll
        for (int j = 0; j < 8; ++j) S += red2[o * 8 + j];
        const float inv = 1.0f / S;
        float* dst = ws + OFF_PH + (size_t)(bp * 32 + o) * 64 + k * 8;
#pragma unroll
        for (int j = 0; j < 8; ++j) dst[j] = e[j] * inv;
    } else {
        // ---------------- pw path ----------------
        const int bid2 = bid - 64;
        const int bp = bid2 >> 3, og = bid2 & 7;
        float* shX = sm;                     // [8 ii][2 kh][514]
        float* shW = sm + 8224;              // [4 oo][32 i][2 kh][3 kw]
        const int wave = tid >> 6, lane = tid & 63;
        const int o = og * 4 + wave;

        for (int idx = tid; idx < 768; idx += 256) shW[idx] = wwt[og * 768 + idx];

        float acc[8];
        {
            const float b = bwt[o];
#pragma unroll
            for (int q = 0; q < 8; ++q) acc[q] = b;
        }

        for (int ic = 0; ic < 4; ++ic) {
            __syncthreads();
            for (int idx = tid; idx < 8192; idx += 256) {
                const int ii = idx >> 10;
                const int rem = idx & 1023;
                const int kh = rem >> 9;
                const int w = rem & 511;
                const int g = (bp * 32 + ic * 8 + ii) * 512 + w;
                const float v = (kh == 0) ? ws[OFF_WSUM + g] * (1.0f / 64.0f)
                                          : ws[OFF_WMAX + g];
                shX[(ii * 2 + kh) * 514 + w + 1] = v;
            }
            if (tid < 16) {
                const int ii = tid >> 1, kh = tid & 1;
                shX[(ii * 2 + kh) * 514 + 0] = 0.f;
                shX[(ii * 2 + kh) * 514 + 513] = 0.f;
            }
            __syncthreads();
#pragma unroll
            for (int ii = 0; ii < 8; ++ii) {
                const int i = ic * 8 + ii;
#pragma unroll
                for (int kh = 0; kh < 2; ++kh) {
                    const float* row = &shX[(ii * 2 + kh) * 514];
                    const float* wr = &shW[wave * 192 + i * 6 + kh * 3];
                    const float w0v = wr[0], w1v = wr[1], w2v = wr[2];
#pragma unroll
                    for (int q = 0; q < 8; ++q) {
                        const int b = q * 64 + lane;
                        const float v0 = row[b];
                        const float v1 = row[b + 1];
                        const float v2 = row[b + 2];
                        acc[q] += w0v * v0 + w1v * v1 + w2v * v2;
                    }
                }
            }
        }
#pragma unroll
        for (int q = 0; q < 8; ++q) acc[q] = fmaxf(acc[q], 0.f);
        float m = acc[0];
#pragma unroll
        for (int q = 1; q < 8; ++q) m = fmaxf(m, acc[q]);
        m = wred_max(m);
        float e[8], s = 0.f;
#pragma unroll
        for (int q = 0; q < 8; ++q) { e[q] = __expf(acc[q] - m); s += e[q]; }
        s = wred_sum(s);
        const float inv = 1.0f / s;
        float* dst = ws + OFF_PW + (size_t)(bp * 32 + o) * 512;
#pragma unroll
        for (int q = 0; q < 8; ++q) dst[q * 64 + lane] = e[q] * inv;
    }
}

// ---------------------------------------------------------------------------
// Kernel 3: apply. One block per (bp, h). coef[o][c]=w_e[o,c]*ph[c,h] in LDS;
// each wave owns 8 o-rows; per row each lane does two contiguous float4 at
// w = lane*4 and w = 256+lane*4 (every load/store instr = contiguous 1 KB).
// out stores are non-temporal so x stays resident in L3 for this kernel's
// second pass over x.
// ---------------------------------------------------------------------------
__global__ __launch_bounds__(256) void k_apply(const float* __restrict__ x,
                                               const float* __restrict__ we,
                                               const float* __restrict__ be,
                                               const float* __restrict__ ws,
                                               float* __restrict__ out) {
    const int bid = blockIdx.x;
    const int bp = bid >> 6;
    const int h = bid & 63;
    const int tid = threadIdx.x;
    const int wave = tid >> 6, lane = tid & 63;

    __shared__ float shPh[32];
    __shared__ float coef[1024];  // [o][c]

    if (tid < 32) shPh[tid] = ws[OFF_PH + (size_t)(bp * 32 + tid) * 64 + h];
    __syncthreads();
    for (int idx = tid; idx < 1024; idx += 256)
        coef[idx] = we[idx] * shPh[idx & 31];
    __syncthreads();

    const int o0 = wave * 8;
    float acc[8][2][4];   // [oo][q][j], w = q*256 + lane*4 + j
#pragma unroll
    for (int oo = 0; oo < 8; ++oo) {
        const float b = be[o0 + oo];
#pragma unroll
        for (int q = 0; q < 2; ++q)
#pragma unroll
            for (int j = 0; j < 4; ++j) acc[oo][q][j] = b;
    }

    const float4* pw4 = (const float4*)(ws + OFF_PW + (size_t)bp * 32 * 512);
    for (int c = 0; c < 32; ++c) {
        const float4 p0 = pw4[c * 128 + lane];        // w = lane*4 .. +3
        const float4 p1 = pw4[c * 128 + 64 + lane];   // w = 256+lane*4 .. +3
#pragma unroll
        for (int oo = 0; oo < 8; ++oo) {
            const float wg = coef[(o0 + oo) * 32 + c];  // wave-uniform broadcast
            acc[oo][0][0] += wg * p0.x; acc[oo][0][1] += wg * p0.y;
            acc[oo][0][2] += wg * p0.z; acc[oo][0][3] += wg * p0.w;
            acc[oo][1][0] += wg * p1.x; acc[oo][1][1] += wg * p1.y;
            acc[oo][1][2] += wg * p1.z; acc[oo][1][3] += wg * p1.w;
        }
    }

#pragma unroll
    for (int oo = 0; oo < 8; ++oo) {
        const size_t rowb = (((size_t)(bp * 32 + o0 + oo)) * 64 + h) * 512;
#pragma unroll
        for (int q = 0; q < 2; ++q) {
            const size_t base = rowb + q * 256 + lane * 4;
            const f4 xv = __builtin_nontemporal_load((const f4*)(x + base));
            f4 r;
#pragma unroll
            for (int j = 0; j < 4; ++j) {
                const float a = acc[oo][q][j];
                const float ex = __expf(-a);
                const float sg = __builtin_amdgcn_rcpf(1.0f + ex);
                r[j] = xv[j] + xv[j] * sg;
            }
            __builtin_nontemporal_store(r, (f4*)(out + base));
        }
    }
}

extern "C" void kernel_launch(void* const* d_in, const int* in_sizes, int n_in,
                              void* d_out, int out_size, void* d_ws, size_t ws_size,
                              hipStream_t stream) {
    const float* x   = (const float*)d_in[0];
    const float* wh  = (const float*)d_in[1];
    const float* bh  = (const float*)d_in[2];
    const float* wwt = (const float*)d_in[3];
    const float* bwt = (const float*)d_in[4];
    const float* we  = (const float*)d_in[5];
    const float* be  = (const float*)d_in[6];
    float* out = (float*)d_out;
    float* ws  = (float*)d_ws;

    k_reduce<<<2048, 256, 0, stream>>>(x, ws);
    k_conv<<<576, 256, 0, stream>>>(wh, bh, wwt, bwt, ws);
    k_apply<<<4096, 256, 0, stream>>>(x, we, be, ws, out);
}